// Round 1
// baseline (43.867 us; speedup 1.0000x reference)
//
#include <hip/hip_runtime.h>
#include <math.h>

// Problem constants
#define B_SZ   8192
#define D_IN   512
#define M0_N   128
#define M1_N   128
#define K_TOP  8
#define H_DIM  128
#define OUT_N  2

// ws header layout (ints):
// [0..1]    idx_out (2 selected layer-1 modules, descending)
// [2..17]   idx1[j*8+k] : top-8 layer-0 module ids feeding layer-1 module j
// [18..33]  mods0[16]   : deduped layer-0 module ids (-1 = empty slot)
// [34..161] map[128]    : layer-0 module id -> slot (-1 if unused)
// [162..289] idx0[s*8+k]: top-8 input dims of x for slot s
// out0t (float) at byte offset 2048: [16][8192] transposed layer-0 outputs

// ---------------------------------------------------------------------------
// Wave-parallel iterative top-k with jax.lax.top_k semantics:
// descending value, ties broken by lowest index.
template<int NCH>
__device__ __forceinline__ void wave_topk(const float* __restrict__ base,
                                          int stride, int k, int* out_idx,
                                          int lane) {
  float v[NCH];
#pragma unroll
  for (int t = 0; t < NCH; ++t) v[t] = base[(t * 64 + lane) * stride];
  for (int r = 0; r < k; ++r) {
    float bv = -INFINITY;
    int bd = 0x7fffffff;
#pragma unroll
    for (int t = 0; t < NCH; ++t) {
      if (v[t] > bv) { bv = v[t]; bd = t * 64 + lane; }
    }
#pragma unroll
    for (int m = 1; m < 64; m <<= 1) {
      float ov = __shfl_xor(bv, m, 64);
      int   od = __shfl_xor(bd, m, 64);
      if (ov > bv || (ov == bv && od < bd)) { bv = ov; bd = od; }
    }
    if (lane == 0) out_idx[r] = bd;
    // clear the winner (static indexing to stay in registers)
    if ((bd & 63) == lane) {
      const int tw = bd >> 6;
#pragma unroll
      for (int tt = 0; tt < NCH; ++tt)
        if (tt == tw) v[tt] = -INFINITY;
    }
  }
}

// ---------------------------------------------------------------------------
__global__ __launch_bounds__(512)
void route_kernel(const int* __restrict__ task_id_p,
                  const float* __restrict__ emb0,
                  const float* __restrict__ emb1,
                  const float* __restrict__ emb_out,
                  int* __restrict__ hdr) {
  __shared__ int s_idx_out[2];
  __shared__ int s_idx1[16];
  __shared__ int s_mods0[16];
  __shared__ int s_map[128];
  __shared__ int s_idx0[128];
  const int tid  = threadIdx.x;
  const int lane = tid & 63;
  const int wid  = tid >> 6;
  const int task = task_id_p[0];

  if (tid < 128) s_map[tid] = -1;
  __syncthreads();

  // Phase 1: top-2 over emb_out[task][:,0]  (M1 values, stride 1)
  if (wid == 0)
    wave_topk<2>(emb_out + task * M1_N, 1, OUT_N, s_idx_out, lane);
  __syncthreads();

  // Phase 2: per selected layer-1 module, top-8 over emb1[task][:, m1]
  if (wid < 2) {
    const int m1 = s_idx_out[wid];
    wave_topk<2>(emb1 + task * M0_N * M1_N + m1, M1_N, K_TOP,
                 s_idx1 + wid * 8, lane);
  }
  __syncthreads();

  // Phase 3: dedup layer-0 modules into slots
  if (tid == 0) {
    int cnt = 0;
    for (int e = 0; e < 16; ++e) {
      const int m = s_idx1[e];
      if (s_map[m] < 0) { s_map[m] = cnt; s_mods0[cnt++] = m; }
    }
    for (int s2 = cnt; s2 < 16; ++s2) s_mods0[s2] = -1;
  }
  __syncthreads();

  // Phase 4: per live slot, top-8 over emb0[task][:, m0]  (512 values)
  for (int s = wid; s < 16; s += 8) {
    const int m0 = s_mods0[s];
    if (m0 >= 0)
      wave_topk<8>(emb0 + task * D_IN * M0_N + m0, M0_N, K_TOP,
                   s_idx0 + s * 8, lane);
  }
  __syncthreads();

  // Write header to global ws
  if (tid < 2)                      hdr[tid]              = s_idx_out[tid];
  if (tid >= 64  && tid < 80)       hdr[2  + (tid - 64)]  = s_idx1[tid - 64];
  if (tid >= 128 && tid < 144)      hdr[18 + (tid - 128)] = s_mods0[tid - 128];
  if (tid >= 192 && tid < 320)      hdr[34 + (tid - 192)] = s_map[tid - 192];
  if (tid >= 320 && tid < 448)      hdr[162 + (tid - 320)] = s_idx0[tid - 320];
}

// ---------------------------------------------------------------------------
// Layer 0 (only live slots): out0t[s][b] = W2[m]·relu(W1[m]·xg + b1[m]) + b2[m]
__global__ __launch_bounds__(256)
void layer0_kernel(const float* __restrict__ x,
                   const float* __restrict__ W1, const float* __restrict__ b1,
                   const float* __restrict__ W2, const float* __restrict__ b2,
                   const int* __restrict__ hdr, float* __restrict__ out0t) {
  const int s  = blockIdx.y;
  const int m0 = hdr[18 + s];
  if (m0 < 0) return;            // uniform per block — safe early exit

  __shared__ float4 sW1[256];    // [k][h4]: k*32 + h4
  __shared__ float4 sB1[32];
  __shared__ float4 sW2[32];
  __shared__ int    sIdx[8];
  __shared__ float  sB2;

  const int tid = threadIdx.x;
  sW1[tid] = ((const float4*)(W1 + m0 * K_TOP * H_DIM))[tid];
  if (tid < 32)       sB1[tid]      = ((const float4*)(b1 + m0 * H_DIM))[tid];
  else if (tid < 64)  sW2[tid - 32] = ((const float4*)(W2 + m0 * H_DIM))[tid - 32];
  else if (tid < 72)  sIdx[tid - 64] = hdr[162 + s * 8 + (tid - 64)];
  else if (tid == 72) sB2 = b2[m0];
  __syncthreads();

  const int b = blockIdx.x * 256 + tid;
  const float* xr = x + (size_t)b * D_IN;
  float xv[8];
#pragma unroll
  for (int k = 0; k < 8; ++k) xv[k] = xr[sIdx[k]];

  float acc = 0.f;
#pragma unroll
  for (int h4 = 0; h4 < 32; ++h4) {
    float4 hv = sB1[h4];
#pragma unroll
    for (int k = 0; k < 8; ++k) {
      const float4 w = sW1[k * 32 + h4];
      hv.x = fmaf(xv[k], w.x, hv.x);
      hv.y = fmaf(xv[k], w.y, hv.y);
      hv.z = fmaf(xv[k], w.z, hv.z);
      hv.w = fmaf(xv[k], w.w, hv.w);
    }
    const float4 w2 = sW2[h4];
    acc = fmaf(fmaxf(hv.x, 0.f), w2.x, acc);
    acc = fmaf(fmaxf(hv.y, 0.f), w2.y, acc);
    acc = fmaf(fmaxf(hv.z, 0.f), w2.z, acc);
    acc = fmaf(fmaxf(hv.w, 0.f), w2.w, acc);
  }
  out0t[s * B_SZ + b] = acc + sB2;
}

// ---------------------------------------------------------------------------
// Layer 1 (2 selected modules) fused with final gather + sigmoid.
__global__ __launch_bounds__(256)
void layer1_kernel(const float* __restrict__ out0t,
                   const float* __restrict__ W1, const float* __restrict__ b1,
                   const float* __restrict__ W2, const float* __restrict__ b2,
                   const int* __restrict__ hdr, float* __restrict__ out) {
  __shared__ float4 sW1[256];
  __shared__ float4 sB1[32];
  __shared__ float4 sW2[32];
  __shared__ int    sSlot[8];
  __shared__ float  sB2;

  const int j   = blockIdx.y;
  const int tid = threadIdx.x;
  const int m1  = hdr[j];

  sW1[tid] = ((const float4*)(W1 + m1 * K_TOP * H_DIM))[tid];
  if (tid < 32)       sB1[tid]      = ((const float4*)(b1 + m1 * H_DIM))[tid];
  else if (tid < 64)  sW2[tid - 32] = ((const float4*)(W2 + m1 * H_DIM))[tid - 32];
  else if (tid < 72) {
    const int m0 = hdr[2 + j * 8 + (tid - 64)];
    sSlot[tid - 64] = hdr[34 + m0];
  }
  else if (tid == 72) sB2 = b2[m1];
  __syncthreads();

  const int b = blockIdx.x * 256 + tid;
  float xv[8];
#pragma unroll
  for (int k = 0; k < 8; ++k) xv[k] = out0t[sSlot[k] * B_SZ + b];  // coalesced

  float acc = 0.f;
#pragma unroll
  for (int h4 = 0; h4 < 32; ++h4) {
    float4 hv = sB1[h4];
#pragma unroll
    for (int k = 0; k < 8; ++k) {
      const float4 w = sW1[k * 32 + h4];
      hv.x = fmaf(xv[k], w.x, hv.x);
      hv.y = fmaf(xv[k], w.y, hv.y);
      hv.z = fmaf(xv[k], w.z, hv.z);
      hv.w = fmaf(xv[k], w.w, hv.w);
    }
    const float4 w2 = sW2[h4];
    acc = fmaf(fmaxf(hv.x, 0.f), w2.x, acc);
    acc = fmaf(fmaxf(hv.y, 0.f), w2.y, acc);
    acc = fmaf(fmaxf(hv.z, 0.f), w2.z, acc);
    acc = fmaf(fmaxf(hv.w, 0.f), w2.w, acc);
  }
  const float val = acc + sB2;
  out[(size_t)b * OUT_N + j] = 1.f / (1.f + __expf(-val));
}

// ---------------------------------------------------------------------------
extern "C" void kernel_launch(void* const* d_in, const int* in_sizes, int n_in,
                              void* d_out, int out_size, void* d_ws, size_t ws_size,
                              hipStream_t stream) {
  const float* x       = (const float*)d_in[0];
  const int*   task_id = (const int*)  d_in[1];
  const float* emb0    = (const float*)d_in[2];
  const float* emb1    = (const float*)d_in[3];
  const float* emb_out = (const float*)d_in[4];
  const float* W1_0    = (const float*)d_in[5];
  const float* b1_0    = (const float*)d_in[6];
  const float* W2_0    = (const float*)d_in[7];
  const float* b2_0    = (const float*)d_in[8];
  const float* W1_1    = (const float*)d_in[9];
  const float* b1_1    = (const float*)d_in[10];
  const float* W2_1    = (const float*)d_in[11];
  const float* b2_1    = (const float*)d_in[12];

  int*   hdr   = (int*)d_ws;
  float* out0t = (float*)((char*)d_ws + 2048);
  float* out   = (float*)d_out;

  route_kernel<<<1, 512, 0, stream>>>(task_id, emb0, emb1, emb_out, hdr);
  layer0_kernel<<<dim3(32, 16), 256, 0, stream>>>(x, W1_0, b1_0, W2_0, b2_0,
                                                  hdr, out0t);
  layer1_kernel<<<dim3(32, 2), 256, 0, stream>>>(out0t, W1_1, b1_1, W2_1, b2_1,
                                                 hdr, out);
}